// Round 14
// baseline (195.835 us; speedup 1.0000x reference)
//
#include <hip/hip_runtime.h>
#include <hip/hip_bf16.h>

// GATConv N=50000, C=64, H=12, E=400000 (+N self loops), x-space aggregation:
//   y[d] = concat_h[ (sum_e w_eh x[s_e]) / (den_h*H) ] @ Wstack,  h never built.
// Structure = R9's proven 3-dispatch:
//   k_pre  : cnt=0 | Wt2[c,h*64+k]=bf16(W[k,h*64+c]) | Vt cols
//   k_main : build adj (SOURCE ids, cap 64) | ax-MFMA a_all=x@V + xb=bf16(x)
//   k_fused: 4 waves x 4 nodes serial. R14 diet (audit: VALUBusy-implied ~45
//     wave-instrs/edge; source said ~27 -> den adds + scalarized f32x2 blamed):
//     (1) w = exp(sc + (lane<deg ? 0 : -1e30)) -> pad lanes contribute EXACT 0;
//         den[h] = 6-step shfl_xor butterfly over the wave's w (72 ops/node on
//         the idle LDS pipe) instead of 12 VALU adds per EDGE.
//     (2) bucketed full unroll (deg<=8 / <=16 / +tail): constant-index
//         readlanes, all xb gathers of a node issued in ONE batch.
//     (3) plain float acc[12] (f32x2 "pk" was scalarizing anyway).
//     R13's dbuf reverted (VGPR 40->48 cost occupancy, no gain).
//     readlane broadcast stays (per-edge LDS traffic lost: R6, R10).
//     zt -> LDS, barrier, 16x64x768 MFMA GEMM + fused relu(x+y+bias).
// No segment_max: exp(s)/sum exp(s) is exact here (logits O(few), fp32 exp).

typedef __bf16 bf16x8 __attribute__((ext_vector_type(8)));
typedef float  f32x4  __attribute__((ext_vector_type(4)));

#define HEADS 12
#define CH 64
#define HC 768
#define CAP 64
#define ACOLS 24      // a_all[n][0..11]=src logits, [12..23]=dst logits
#define ZSTRIDE 776   // zt row stride (bf16)

__device__ inline float readlane_f(float v, int lane) {
    return __builtin_bit_cast(float,
        __builtin_amdgcn_readlane(__builtin_bit_cast(int, v), lane));
}

__global__ __launch_bounds__(256) void k_pre(
    const float* __restrict__ W,
    const float* __restrict__ att_src, const float* __restrict__ att_dst,
    int* __restrict__ cnt, __bf16* __restrict__ Wt2, __bf16* __restrict__ Vt,
    int N) {
    const int nb_z = (N + 255) >> 8;
    const int nb_w = (CH * HC) >> 8;           // 192
    int b = blockIdx.x, tid = threadIdx.x;
    if (b < nb_z) {                            // ---- cnt = 0 ----
        int i = b * 256 + tid;
        if (i < N) cnt[i] = 0;
        return;
    }
    b -= nb_z;
    if (b < nb_w) {                            // ---- Wt2 transpose ----
        int t = b * 256 + tid;
        int c = t / HC, kk = t % HC;
        int k = kk & 63;
        Wt2[t] = (__bf16)W[(size_t)k * HC + (kk - k) + c];
        return;
    }
    b -= nb_w;                                 // ---- Vt col b (0..31) ----
    if (b >= 2 * HEADS) {
        if (tid < CH) Vt[b * CH + tid] = (__bf16)0.f;
        return;
    }
    const float* att = (b < HEADS) ? att_src + b * CH
                                   : att_dst + (b - HEADS) * CH;
    int k = tid >> 2, cq = tid & 3;            // 64 k-rows x 4 c-quarters
    const float* wr = W + (size_t)k * HC + (b % HEADS) * CH + cq * 16;
    float s = 0.f;
#pragma unroll
    for (int j = 0; j < 16; ++j) s += wr[j] * att[cq * 16 + j];
    s += __shfl_xor(s, 1, 64);
    s += __shfl_xor(s, 2, 64);
    if (cq == 0) Vt[b * CH + k] = (__bf16)s;
}

__global__ __launch_bounds__(256) void k_main(
    const float* __restrict__ x, const int* __restrict__ ei,
    const __bf16* __restrict__ Vt,
    int* __restrict__ cnt, int* __restrict__ adj,
    __bf16* __restrict__ xb, float* __restrict__ a_all, int N, int E) {
    const int EP = E + N;
    const int nb_build = (EP + 255) >> 8;
    int b = blockIdx.x, tid = threadIdx.x;

    if (b < nb_build) {                        // ---- adjacency: SOURCE ids ----
        int e = b * 256 + tid;
        if (e < EP) {
            int d, s;
            if (e < E) { d = ei[E + e]; s = ei[e]; }
            else       { d = e - E;     s = d; }
            int pos = atomicAdd(&cnt[d], 1);
            if (pos < CAP) adj[d * CAP + pos] = s;
        }
        return;
    }
    b -= nb_build;                             // ---- a_all = x@V + xb ----
    int wave = tid >> 6, lane = tid & 63;
    int m = lane & 15, quad = lane >> 4;
    int m0 = b * 64 + wave * 16;
    int row = m0 + m;
    int rc = row < N ? row : N - 1;
    const float* xa = x + (size_t)rc * CH + quad * 8;
    f32x4 v0 = *(const f32x4*)xa;
    f32x4 v1 = *(const f32x4*)(xa + 4);
    f32x4 v2 = *(const f32x4*)(xa + 32);
    f32x4 v3 = *(const f32x4*)(xa + 36);
    bf16x8 a0, a1;
#pragma unroll
    for (int j = 0; j < 4; ++j) {
        a0[j] = (__bf16)v0[j]; a0[4 + j] = (__bf16)v1[j];
        a1[j] = (__bf16)v2[j]; a1[4 + j] = (__bf16)v3[j];
    }
    if (row < N) {                             // fused xb = bf16(x)
        *(bf16x8*)(xb + (size_t)row * CH + quad * 8) = a0;
        *(bf16x8*)(xb + (size_t)row * CH + quad * 8 + 32) = a1;
    }
#pragma unroll
    for (int t = 0; t < 2; ++t) {              // two 16-col tiles -> 24 cols
        const __bf16* bp = Vt + (size_t)(t * 16 + m) * CH + quad * 8;
        bf16x8 b0 = *(const bf16x8*)bp;
        bf16x8 b1 = *(const bf16x8*)(bp + 32);
        f32x4 acc = {0.f, 0.f, 0.f, 0.f};
        acc = __builtin_amdgcn_mfma_f32_16x16x32_bf16(a0, b0, acc, 0, 0, 0);
        acc = __builtin_amdgcn_mfma_f32_16x16x32_bf16(a1, b1, acc, 0, 0, 0);
        int col = t * 16 + m;
        if (col < ACOLS) {
#pragma unroll
            for (int r = 0; r < 4; ++r) {
                int rr = m0 + quad * 4 + r;
                if (rr < N) a_all[(size_t)rr * ACOLS + col] = acc[r];
            }
        }
    }
}

// NE edges fully unrolled: constant-index readlanes, one gather batch.
template <int NE>
__device__ __forceinline__ void agg_edges(int s_l, const float* w,
                                          const __bf16* __restrict__ xb,
                                          int lane, float* acc) {
    float xv[NE];
#pragma unroll
    for (int e = 0; e < NE; ++e) {
        int s = __builtin_amdgcn_readlane(s_l, e);
        xv[e] = (float)xb[(size_t)s * CH + lane];
    }
#pragma unroll
    for (int e = 0; e < NE; ++e) {
#pragma unroll
        for (int hh = 0; hh < HEADS; ++hh)
            acc[hh] += readlane_f(w[hh], e) * xv[e];
    }
}

__global__ __launch_bounds__(256) void k_fused(
    const int* __restrict__ cnt, const int* __restrict__ adj,
    const float* __restrict__ a_all,
    const __bf16* __restrict__ xb, const __bf16* __restrict__ Wt2,
    const float* __restrict__ x, const float* __restrict__ bias,
    float* __restrict__ out, int N) {
    __shared__ __bf16 zt[16 * ZSTRIDE];
    int wave = threadIdx.x >> 6, lane = threadIdx.x & 63;
    int base = blockIdx.x * 16;

    // ---- prologue: 4 nodes' cnt + adj[0..31] in parallel ----
    int degj[4], slj[4];
#pragma unroll
    for (int j = 0; j < 4; ++j) {
        int d = base + wave * 4 + j;
        int dg = cnt[d];
        degj[j] = dg < CAP ? dg : CAP;
        int sraw = (lane < 32) ? adj[d * CAP + lane] : 0;
        slj[j] = sraw < 0 ? 0 : (sraw >= N ? N - 1 : sraw);
    }
    // rare (P(Poisson(9)>32)~1e-9): fetch upper half of adj row
#pragma unroll
    for (int j = 0; j < 4; ++j) {
        if (degj[j] > 32 && lane >= 32) {
            int sraw = adj[(base + wave * 4 + j) * CAP + lane];
            slj[j] = sraw < 0 ? 0 : (sraw >= N ? N - 1 : sraw);
        }
    }

    for (int j = 0; j < 4; ++j) {
        int row = wave * 4 + j;
        int d = base + row;
        int deg = degj[j];
        int s_l = slj[j];

        // ---- phase 1: 12 weights; lanes >= deg get w == 0 exactly ----
        float w[HEADS];
        {
            const f32x4* pa = (const f32x4*)(a_all + (size_t)d * ACOLS + HEADS);
            f32x4 d0 = pa[0], d1 = pa[1], d2 = pa[2];
            const f32x4* ps = (const f32x4*)(a_all + (size_t)s_l * ACOLS);
            f32x4 s0 = ps[0], s1 = ps[1], s2 = ps[2];
            float pad = (lane < deg) ? 0.f : -1e30f;   // exp(-1e30) == 0
#pragma unroll
            for (int u = 0; u < 4; ++u) {
                float sc;
                sc = s0[u] + d0[u]; sc = sc > 0.f ? sc : 0.2f * sc;
                w[u] = __expf(sc + pad);
                sc = s1[u] + d1[u]; sc = sc > 0.f ? sc : 0.2f * sc;
                w[4 + u] = __expf(sc + pad);
                sc = s2[u] + d2[u]; sc = sc > 0.f ? sc : 0.2f * sc;
                w[8 + u] = __expf(sc + pad);
            }
        }

        // ---- den via 6-step butterfly (LDS pipe; w==0 past deg) ----
        float den[HEADS];
#pragma unroll
        for (int hh = 0; hh < HEADS; ++hh) {
            float s = w[hh];
            s += __shfl_xor(s, 1, 64);
            s += __shfl_xor(s, 2, 64);
            s += __shfl_xor(s, 4, 64);
            s += __shfl_xor(s, 8, 64);
            s += __shfl_xor(s, 16, 64);
            s += __shfl_xor(s, 32, 64);
            den[hh] = s;
        }

        // ---- phase 2: bucketed unrolled gather + fmac ----
        float acc[HEADS];
#pragma unroll
        for (int hh = 0; hh < HEADS; ++hh) acc[hh] = 0.f;
        if (deg <= 8) {
            agg_edges<8>(s_l, w, xb, lane, acc);
        } else {
            agg_edges<16>(s_l, w, xb, lane, acc);
            for (int i = 16; i < deg; ++i) {           // P(deg>16) ~ 2%
                int s = __builtin_amdgcn_readlane(s_l, i);
                float xv = (float)xb[(size_t)s * CH + lane];
#pragma unroll
                for (int hh = 0; hh < HEADS; ++hh)
                    acc[hh] += readlane_f(w[hh], i) * xv;
            }
        }

        __bf16* zr = zt + row * ZSTRIDE + lane;
#pragma unroll
        for (int hh = 0; hh < HEADS; ++hh)
            zr[hh * CH] = (__bf16)(acc[hh] * (1.0f / ((den[hh] + 1e-16f) * HEADS)));
    }

    __syncthreads();

    // ---- phase 3: 16x64x768 GEMM; wave = one 16-col tile ----
    {
        int m = lane & 15, quad = lane >> 4;
        int n0 = wave * 16;
        const __bf16* za = zt + m * ZSTRIDE + quad * 8;
        const __bf16* wb = Wt2 + (size_t)(n0 + m) * HC + quad * 8;
        f32x4 acc = {0.f, 0.f, 0.f, 0.f};
#pragma unroll
        for (int kc = 0; kc < HC; kc += 32) {
            bf16x8 a  = *(const bf16x8*)(za + kc);
            bf16x8 bf = *(const bf16x8*)(wb + kc);
            acc = __builtin_amdgcn_mfma_f32_16x16x32_bf16(a, bf, acc, 0, 0, 0);
        }
        int col = n0 + m;
        float bv = bias[col];
#pragma unroll
        for (int r = 0; r < 4; ++r) {
            int dd = base + quad * 4 + r;
            if (dd < N) {
                float o = x[(size_t)dd * CH + col] + acc[r] + bv;
                out[(size_t)dd * CH + col] = fmaxf(o, 0.f);
            }
        }
    }
}

extern "C" void kernel_launch(void* const* d_in, const int* in_sizes, int n_in,
                              void* d_out, int out_size, void* d_ws, size_t ws_size,
                              hipStream_t stream) {
    const float* x       = (const float*)d_in[0];
    const int*   ei      = (const int*)d_in[1];
    const float* W       = (const float*)d_in[2];
    const float* att_src = (const float*)d_in[3];
    const float* att_dst = (const float*)d_in[4];
    const float* bias    = (const float*)d_in[5];
    float* out = (float*)d_out;

    int N = in_sizes[0] / CH;   // 50000
    int E = in_sizes[1] / 2;    // 400000
    int EP = E + N;

    char* ws = (char*)d_ws;
    size_t off = 0;
    auto take = [&](size_t bytes) -> void* {
        void* p = ws + off;
        off = (off + bytes + 255) & ~(size_t)255;
        return p;
    };
    __bf16* xb    = (__bf16*)take((size_t)N * CH * sizeof(__bf16));
    __bf16* Wt2   = (__bf16*)take((size_t)CH * HC * sizeof(__bf16));
    __bf16* Vt    = (__bf16*)take((size_t)32 * CH * sizeof(__bf16));
    float*  a_all = (float*)take((size_t)N * ACOLS * sizeof(float));
    int*    adj   = (int*)take((size_t)N * CAP * sizeof(int));
    int*    cnt   = (int*)take((size_t)N * sizeof(int));

    const int nb_z     = (N + 255) / 256;
    const int nb_w     = (CH * HC) / 256;
    const int nb_build = (EP + 255) / 256;
    const int nb_ax    = (N + 63) / 64;

    k_pre<<<nb_z + nb_w + 32, 256, 0, stream>>>(W, att_src, att_dst, cnt, Wt2, Vt, N);
    k_main<<<nb_build + nb_ax, 256, 0, stream>>>(x, ei, Vt, cnt, adj, xb, a_all, N, E);
    k_fused<<<(N + 15) / 16, 256, 0, stream>>>(cnt, adj, a_all, xb, Wt2, x, bias, out, N);
}